// Round 19
// baseline (57.544 us; speedup 1.0000x reference)
//
#include <hip/hip_runtime.h>
#include <math.h>
#include <stdint.h>

// Problem: ProcessFeatures_83296595738632
// corr[bs,bg,i] = sum_{h,j,k} sat[bs,h,(i+j)%64,k] * grd[bg,h,j,15-k]
// orien = argmax_i corr (first-max); dot with cyclic shift orien, /||sat||
// distance[bg,bs] = 2-2*dot[bs,bg]; out: sat | grd | distance | orien(float)
//
// R19: M-SPLIT for wave count. corr grid (6 nt x 96 bs x 2 mh) = 1152 blocks
// x 8 waves = 9216 waves (9/SIMD: slots saturated). Each block computes its
// 32 shift-rows FULLY (no K partials) + local argmax -> (max,idx) pair in ws
// (16B per bs,bg,mh). Epilogue: 2-way max-merge + verified fp32 dot/distance.
// bf16x4 numerics and all fragment layouts verbatim from verified R12/R18.

#define BS   96
#define H    4
#define W    64
#define C    16
#define BG   96
#define HWC  (H*W*C)                  // 4096

#define SAT_ELEMS (BS*H*W*C)          // 393216
#define OUT_DIST  (2*SAT_ELEMS)       // 786432
#define OUT_ORIEN (OUT_DIST + BS*BG)  // 795648

#define WS_MI_OFF   ((size_t)2 * SAT_ELEMS * 2)        // 1.5 MB (Bpk)
#define WS_NORM_OFF (WS_MI_OFF + (size_t)BS * BG * 2 * 2 * 4)   // +294912
#define WS_NEEDED   (WS_NORM_OFF + 512)

typedef __attribute__((ext_vector_type(4)))  short short4v;
typedef __attribute__((ext_vector_type(8)))  short short8v;
typedef __attribute__((ext_vector_type(4)))  float f32x4;

__device__ __forceinline__ void bsplit(float x, unsigned short& hi, unsigned short& lo) {
    unsigned int u = __float_as_uint(x);
    unsigned int r = (u + 0x7FFFu + ((u >> 16) & 1u)) >> 16;   // RNE to bf16
    hi = (unsigned short)r;
    float hf = __uint_as_float(r << 16);
    float l = x - hf;
    unsigned int ul = __float_as_uint(l);
    unsigned int rl = (ul + 0x7FFFu + ((ul >> 16) & 1u)) >> 16;
    lo = (unsigned short)rl;
}

// ---------------- prologue: pack B fragments (16x16x32 layout), norms,
//                  passthrough copies ----------------
// Fragment (j,kh,nt6,pl): lane l, elem e ->
//   B[k = (l>>4)*8+e][col = l&15] = grdR[j][nt6*16 + (l&15)][kh*32 + (l>>4)*8 + e]
//   grdR[j][bg][hk] = grd[bg][hk>>4][j][15-(hk&15)]
__global__ __launch_bounds__(512)
void pf_pack_b(const float* __restrict__ sat, const float* __restrict__ grd,
               unsigned short* __restrict__ Bpk, float* __restrict__ norms,
               float* __restrict__ out)
{
    __shared__ float nred[8];
    const int tid = threadIdx.x;
    const int t = blockIdx.x * 512 + tid;    // < 49152 = 64j * 2kh * 6nt * 64lane

    // ---- fragment packing (R12/R18-verified) ----
    {
        int lane = t & 63;
        int f    = t >> 6;            // fragment id: ((j*2+kh)*6 + nt6)
        int nt6  = f % 6;
        int g    = f / 6;
        int kh   = g & 1;
        int j    = g >> 1;

        int col = nt6 * 16 + (lane & 15);
        int u   = lane >> 4;
        int h   = kh * 2 + (u >> 1);
        int k0  = (u & 1) * 8;        // hk = kh*32 + u*8 -> within-h offset k0

        const float* row = grd + ((size_t)(col * 4 + h) * 64 + j) * 16 + (8 - k0);
        float tmp[8];
        *(float4*)&tmp[0] = *(const float4*)(row);
        *(float4*)&tmp[4] = *(const float4*)(row + 4);

        short8v hv, lv;
        #pragma unroll
        for (int e = 0; e < 8; ++e) {
            unsigned short hi, lo;
            bsplit(tmp[7 - e], hi, lo);      // value[e] = grd[...][15-k0-e]
            hv[e] = (short)hi; lv[e] = (short)lo;
        }
        size_t base = (size_t)f << 10;       // 1024 ushorts per fragment pair
        *(short8v*)&Bpk[base + lane * 8]       = hv;   // plane 0 (hi)
        *(short8v*)&Bpk[base + 512 + lane * 8] = lv;   // plane 1 (lo)
    }

    // ---- norm of sat[bs = blockIdx.x] (R16-verified) ----
    {
        const int wv = tid >> 6, lane = tid & 63;
        float np = 0.f;
        const float4* sb = (const float4*)(sat + (size_t)blockIdx.x * HWC);
        #pragma unroll
        for (int x = tid; x < 1024; x += 512) {
            float4 v = sb[x];
            np = fmaf(v.x, v.x, fmaf(v.y, v.y, fmaf(v.z, v.z, fmaf(v.w, v.w, np))));
        }
        #pragma unroll
        for (int off = 32; off; off >>= 1) np += __shfl_xor(np, off);
        if (lane == 0) nred[wv] = np;
        __syncthreads();
        if (tid == 0) {
            float s = ((nred[0] + nred[1]) + (nred[2] + nred[3]))
                    + ((nred[4] + nred[5]) + (nred[6] + nred[7]));
            norms[blockIdx.x] = sqrtf(s + 1e-8f);
        }
    }

    // ---- passthrough copies ----
    {
        const float4* s4 = (const float4*)sat;
        const float4* g4 = (const float4*)grd;
        float4* o4 = (float4*)out;
        #pragma unroll
        for (int idx = t; idx < 2 * SAT_ELEMS / 4; idx += 49152) {
            o4[idx] = (idx < SAT_ELEMS / 4) ? s4[idx] : g4[idx - SAT_ELEMS / 4];
        }
    }
}

// ---------------- corr (M-split): 32 rows per block + local argmax ----------
#define MFMA16(a, b, c) __builtin_amdgcn_mfma_f32_16x16x32_bf16((a), (b), (c), 0, 0, 0)

__global__ __launch_bounds__(512, 8)
void pf_corrm(const float* __restrict__ sat, const unsigned short* __restrict__ Bpk,
              float* __restrict__ mi)
{
    __shared__ unsigned short sHi[4096], sLo[4096];   // satM planes (16 KB)
    __shared__ float corrPart[4][32][17];             // 8.5 KB

    const int nt6 = blockIdx.x;          // 16-bg group
    const int bs  = blockIdx.y;
    const int mh  = blockIdx.z;          // M half: rows [mh*32, mh*32+32)
    const int bg0 = nt6 * 16;
    const int tid = threadIdx.x;
    const int wv  = tid >> 6, lane = tid & 63;
    const int u   = lane >> 4, l15 = lane & 15, l31 = lane & 31;
    const int mt  = wv & 1;              // mtile within half
    const int kq  = wv >> 1;             // j-slice of 16

    // ---- stage satM (swizzled bf16 hi/lo) ----
    // satM[w][hk] = sat[bs][hk>>4][w][hk&15]; chunk cc=hk>>3 at slot cc^(w&7)
    {
        const float4* satB = (const float4*)(sat + (size_t)bs * HWC);
        #pragma unroll
        for (int x = tid; x < 1024; x += 512) {
            float4 v = satB[x];
            int e = 4 * x;
            int h = e >> 10, w = (e >> 4) & 63, k = e & 15;
            int cc = (h * 16 + k) >> 3;
            int dst = w * 64 + ((cc ^ (w & 7)) * 8) + (k & 7);
            short4v hvv, lvv;
            unsigned short hi, lo;
            bsplit(v.x, hi, lo); hvv[0] = hi; lvv[0] = lo;
            bsplit(v.y, hi, lo); hvv[1] = hi; lvv[1] = lo;
            bsplit(v.z, hi, lo); hvv[2] = hi; lvv[2] = lo;
            bsplit(v.w, hi, lo); hvv[3] = hi; lvv[3] = lo;
            *(short4v*)&sHi[dst] = hvv;
            *(short4v*)&sLo[dst] = lvv;
        }
    }
    __syncthreads();

    // ---- corr GEMM: 1 mtile per wave, j-slice of 16, 2 chains ----
    f32x4 c0 = {0.f,0.f,0.f,0.f}, c1 = {0.f,0.f,0.f,0.f};
    const int m = mh * 2 + mt;
    const int mbase = m * 16 + l15;

    #pragma unroll 4
    for (int jj = 0; jj < 16; ++jj) {
        const int j = kq * 16 + jj;
        const int r = (mbase + j) & 63;
        const int arow = r << 6;
        const int rsw = r & 7;
        #pragma unroll
        for (int kh = 0; kh < 2; ++kh) {
            const unsigned short* bp =
                Bpk + (((size_t)((j * 2 + kh) * 6 + nt6)) << 10) + lane * 8;
            short8v bh = *(const short8v*)bp;
            short8v bl = *(const short8v*)(bp + 512);
            const int cc = kh * 4 + u;
            const int aoff = arow + ((cc ^ rsw) << 3);
            short8v ah = *(const short8v*)&sHi[aoff];
            short8v al = *(const short8v*)&sLo[aoff];
            c0 = MFMA16(ah, bh, c0);
            c1 = MFMA16(ah, bl, c1);
            c1 = MFMA16(al, bh, c1);
            c0 = MFMA16(al, bl, c0);
        }
    }
    f32x4 acc = c0 + c1;

    // ---- C/D -> corrPart[kq]: local row = mt*16 + u*4 + reg, col = l15 ----
    {
        const int rr = mt * 16 + u * 4;
        #pragma unroll
        for (int reg = 0; reg < 4; ++reg)
            corrPart[kq][rr + reg][l15] = acc[reg];
    }
    __syncthreads();

    // ---- kq-reduce + per-bg max/argmax over local 32 rows ----
    // wave wv -> bgc = wv*2..+1; lanes duplicate rows via l31; 5-round reduce
    #pragma unroll
    for (int t = 0; t < 2; ++t) {
        const int bgc = wv * 2 + t;
        float v = (corrPart[0][l31][bgc] + corrPart[1][l31][bgc])
                + (corrPart[2][l31][bgc] + corrPart[3][l31][bgc]);
        int idx = mh * 32 + l31;
        #pragma unroll
        for (int off = 16; off; off >>= 1) {
            float ov = __shfl_xor(v, off);
            int   oi = __shfl_xor(idx, off);
            if (ov > v || (ov == v && oi < idx)) { v = ov; idx = oi; }
        }
        if (lane == 0) {
            float2 p = make_float2(v, (float)idx);
            *(float2*)&mi[((size_t)(bs * BG + bg0 + bgc) * 2 + mh) * 2] = p;
        }
    }
}

// ---------------- epilogue: 2-way merge + fp32 dot + distance ----------
__global__ __launch_bounds__(512)
void pf_epim(const float* __restrict__ sat, const float* __restrict__ grd,
             const float* __restrict__ mi, const float* __restrict__ norms,
             float* __restrict__ out)
{
    const int nt6 = blockIdx.x;
    const int bs  = blockIdx.y;
    const int bg0 = nt6 * 16;
    const int tid = threadIdx.x;
    const int wv  = tid >> 6, lane = tid & 63;

    const float nrm = norms[bs];

    #pragma unroll
    for (int t = 0; t < 2; ++t) {
        const int bg = bg0 + wv * 2 + t;
        float2 p0 = *(const float2*)&mi[((size_t)(bs * BG + bg) * 2 + 0) * 2];
        float2 p1 = *(const float2*)&mi[((size_t)(bs * BG + bg) * 2 + 1) * 2];
        // numpy first-max: mh0 holds lower indices -> >= favors it
        const float idxf = (p0.x >= p1.x) ? p0.y : p1.y;
        const int orien = (int)idxf;
        if (lane == 0)
            out[OUT_ORIEN + bs * BG + bg] = idxf;

        const int r = (lane + orien) & 63;
        float s = 0.f;
        #pragma unroll
        for (int h = 0; h < 4; ++h) {
            const float4* sp = (const float4*)&sat[(((size_t)bs * 4 + h) * 64 + r) * 16];
            const float4* gp = (const float4*)&grd[(((size_t)bg * 4 + h) * 64 + lane) * 16];
            #pragma unroll
            for (int c4 = 0; c4 < 4; ++c4) {
                float4 sv = sp[c4];
                float4 gv = gp[c4];
                s = fmaf(sv.x, gv.x, fmaf(sv.y, gv.y, fmaf(sv.z, gv.z, fmaf(sv.w, gv.w, s))));
            }
        }
        #pragma unroll
        for (int off = 32; off; off >>= 1) s += __shfl_xor(s, off);
        if (lane == 0)
            out[OUT_DIST + (size_t)bg * BS + bs] = 2.f - 2.f * (s / nrm);
    }
}

// ---------------- fallback (R3, verified): used only if ws too small ----------------
__device__ __forceinline__ int satIdxFB(int hw, int c4) {
    return hw * 16 + 4 * ((c4 + (hw >> 1)) & 3);
}
__device__ __forceinline__ float rot_add(int baddr, float p) {
    return __int_as_float(__builtin_amdgcn_ds_bpermute(baddr, __float_as_int(p)));
}
__device__ __forceinline__ float dot_rev(const float4 s0, const float4 s1,
                                         const float4 s2, const float4 s3,
                                         const float* __restrict__ g) {
    float p0 = fmaf(s0.x, g[15], fmaf(s0.y, g[14], fmaf(s0.z, g[13], s0.w * g[12])));
    float p1 = fmaf(s1.x, g[11], fmaf(s1.y, g[10], fmaf(s1.z, g[ 9], s1.w * g[ 8])));
    float p2 = fmaf(s2.x, g[ 7], fmaf(s2.y, g[ 6], fmaf(s2.z, g[ 5], s2.w * g[ 4])));
    float p3 = fmaf(s3.x, g[ 3], fmaf(s3.y, g[ 2], fmaf(s3.z, g[ 1], s3.w * g[ 0])));
    return (p0 + p1) + (p2 + p3);
}
#define NB 8
__global__ __launch_bounds__(256)
void pf_fused_fb(const float* __restrict__ sat, const float* __restrict__ grd,
                 float* __restrict__ out)
{
    __shared__ float satL[H * W * C];
    __shared__ float partL[NB * 4 * W];
    __shared__ float sumL[4];
    __shared__ float dotP[NB * 4];
    __shared__ int   orienL[NB];
    const int bs = blockIdx.y, bg0 = blockIdx.x * NB;
    const int tid = threadIdx.x, wv = tid >> 6, lane = tid & 63;
    const float4* sp = (const float4*)(sat + (((size_t)bs * H + wv) * W + lane) * C);
    const float4 s0 = sp[0], s1 = sp[1], s2 = sp[2], s3 = sp[3];
    { const int hw = wv * W + lane;
      *(float4*)&satL[satIdxFB(hw,0)] = s0; *(float4*)&satL[satIdxFB(hw,1)] = s1;
      *(float4*)&satL[satIdxFB(hw,2)] = s2; *(float4*)&satL[satIdxFB(hw,3)] = s3; }
    { float a = fmaf(s0.x,s0.x,fmaf(s0.y,s0.y,fmaf(s0.z,s0.z,s0.w*s0.w)));
      float b = fmaf(s1.x,s1.x,fmaf(s1.y,s1.y,fmaf(s1.z,s1.z,s1.w*s1.w)));
      float c = fmaf(s2.x,s2.x,fmaf(s2.y,s2.y,fmaf(s2.z,s2.z,s2.w*s2.w)));
      float d = fmaf(s3.x,s3.x,fmaf(s3.y,s3.y,fmaf(s3.z,s3.z,s3.w*s3.w)));
      float s = (a+b)+(c+d);
      #pragma unroll
      for (int off = 32; off; off >>= 1) s += __shfl_xor(s, off);
      if (lane == 0) sumL[wv] = s; }
    const float* gpB = grd + (size_t)(bg0 * H + wv) * W * C;
    #pragma unroll
    for (int bp = 0; bp < NB/2; ++bp) {
        const float* gA = gpB + (2*bp) * HWC;
        const float* gB2 = gpB + (2*bp+1) * HWC;
        float accA = 0.f, accB = 0.f;
        int baddr = lane << 2;
        #pragma unroll 2
        for (int j = 0; j < W; ++j) {
            float pA = dot_rev(s0,s1,s2,s3, gA + j*C);
            float pB = dot_rev(s0,s1,s2,s3, gB2 + j*C);
            accA += rot_add(baddr, pA); accB += rot_add(baddr, pB);
            baddr = (baddr + 4) & 255;
        }
        partL[((2*bp)*4 + wv)*W + lane] = accA;
        partL[((2*bp+1)*4 + wv)*W + lane] = accB;
    }
    __syncthreads();
    for (int b = wv; b < NB; b += 4) {
        float v = (partL[(b*4+0)*W+lane] + partL[(b*4+1)*W+lane])
                + (partL[(b*4+2)*W+lane] + partL[(b*4+3)*W+lane]);
        int idx = lane;
        #pragma unroll
        for (int off = 32; off; off >>= 1) {
            float ov = __shfl_xor(v, off); int oi = __shfl_xor(idx, off);
            if (ov > v || (ov == v && oi < idx)) { v = ov; idx = oi; }
        }
        if (lane == 0) { orienL[b] = idx; out[OUT_ORIEN + bs*BG + (bg0+b)] = (float)idx; }
    }
    __syncthreads();
    const float nrm = sqrtf(sumL[0]+sumL[1]+sumL[2]+sumL[3] + 1e-8f);
    { float dp[NB];
      #pragma unroll
      for (int b = 0; b < NB; ++b) {
          const int row = (lane + orienL[b]) & 63;
          const float* gRow = grd + (((size_t)(bg0+b)*H + wv)*W + lane)*C;
          float s = 0.f;
          #pragma unroll
          for (int c4 = 0; c4 < 4; ++c4) {
              float4 sv = *(const float4*)&satL[satIdxFB(wv*W+row, c4)];
              float4 gv = *(const float4*)(gRow + 4*c4);
              s = fmaf(sv.x,gv.x, fmaf(sv.y,gv.y, fmaf(sv.z,gv.z, fmaf(sv.w,gv.w, s))));
          }
          dp[b] = s;
      }
      #pragma unroll
      for (int b = 0; b < NB; ++b) {
          float s = dp[b];
          #pragma unroll
          for (int off = 32; off; off >>= 1) s += __shfl_xor(s, off);
          if (lane == 0) dotP[b*4 + wv] = s;
      } }
    __syncthreads();
    if (tid < NB) {
        float d = ((dotP[tid*4+0]+dotP[tid*4+1])+(dotP[tid*4+2]+dotP[tid*4+3])) / nrm;
        out[OUT_DIST + (size_t)(bg0+tid)*BS + bs] = 2.f - 2.f*d;
    }
}

extern "C" void kernel_launch(void* const* d_in, const int* in_sizes, int n_in,
                              void* d_out, int out_size, void* d_ws, size_t ws_size,
                              hipStream_t stream) {
    const float* sat = (const float*)d_in[0];
    const float* grd = (const float*)d_in[1];
    float* out = (float*)d_out;

    if (ws_size < WS_NEEDED) {
        hipMemcpyAsync(out,             sat, (size_t)SAT_ELEMS * sizeof(float),
                       hipMemcpyDeviceToDevice, stream);
        hipMemcpyAsync(out + SAT_ELEMS, grd, (size_t)SAT_ELEMS * sizeof(float),
                       hipMemcpyDeviceToDevice, stream);
        dim3 grid(BG / NB, BS);
        pf_fused_fb<<<grid, 256, 0, stream>>>(sat, grd, out);
        return;
    }

    unsigned short* Bpk   = (unsigned short*)d_ws;
    float*          mi    = (float*)((char*)d_ws + WS_MI_OFF);
    float*          norms = (float*)((char*)d_ws + WS_NORM_OFF);

    pf_pack_b<<<96, 512, 0, stream>>>(sat, grd, Bpk, norms, out);
    pf_corrm<<<dim3(6, BS, 2), 512, 0, stream>>>(sat, Bpk, mi);
    pf_epim<<<dim3(6, BS), 512, 0, stream>>>(sat, grd, mi, norms, out);
}